// Round 6
// baseline (114.789 us; speedup 1.0000x reference)
//
#include <hip/hip_runtime.h>
#include <cstdint>
#include <cstddef>

// Problem constants
#define NCLUS 64
#define DIM   128
#define BATCH 512              // K of the Gram reduction (bytes per fp8 row)
#define QCOLS 8192             // NCLUS*DIM
#define NBLK2 1024             // two-pair blocks: sum_J ceil((63-J)/2) = 1024
#define TSTRB (QCOLS * BATCH)  // BYTES per tensor in fp8 (4,194,304)
#define FP8SCALE 256.0f        // q^2 * 256 -> e4m3 (max 256 < 448, no clip)

typedef float f32x16 __attribute__((ext_vector_type(16)));
typedef int   i32x4  __attribute__((ext_vector_type(4)));
typedef int   i32x8  __attribute__((ext_vector_type(8)));

// q2t layout: row (t, c*128+d) of 512 bytes over b, PLAIN byte order.
// LDS rows store the 4 16-B chunks of each 64-B k-slice rotated by
// rot(r)=(r+(r>>2))&3 (bank-checked: 2-way = free); achieved by
// pre-swizzling the GLOBAL source address (LDS dest linear).

__device__ __forceinline__ void ld_lds16(const void* g, void* l) {
  __builtin_amdgcn_global_load_lds(
      (__attribute__((address_space(1))) void*)g,
      (__attribute__((address_space(3))) void*)l, 16, 0, 0);
}

// raw v_sqrt_f32 (1-2 ULP) — validated R5: sqrtf's IEEE fixup was ~13us.
#define FSQRT(x) __builtin_amdgcn_sqrtf(x)

#define VM6_BAR() asm volatile("s_waitcnt vmcnt(6)\n\ts_barrier" ::: "memory")
#define VM0_BAR() asm volatile("s_waitcnt vmcnt(0)\n\ts_barrier" ::: "memory")

// ---------------------------------------------------------------------------
// Kernel 1: softmax over D=128 -> q^2*256 -> fp8 e4m3 -> transposed q2t
// (plain byte order). EXACT round-0 structure — known good; do not touch.
// ---------------------------------------------------------------------------
__global__ __launch_bounds__(256) void softmax_q2_kernel(
    const float* __restrict__ emb, uint8_t* __restrict__ q2t,
    float* __restrict__ dotPart) {
  __shared__ uint32_t T32[2 * 64 * 33];      // 16.5 KB; [t*64+b][col] stride 33
  __shared__ float red[4];
  const int c  = blockIdx.y;
  const int bq = blockIdx.x;
  const int tid = threadIdx.x;
  const int w = tid >> 6, lane = tid & 63;
  const int sub = lane >> 5;                 // which of the 2 rows this iter
  const int col = lane & 31;                 // float4 index within the row

  float4 qa = {0.f, 0.f, 0.f, 0.f};
  float dot = 0.f;

#pragma unroll
  for (int k = 0; k < 16; ++k) {
    const int t  = k & 1;
    const int bl = w * 16 + (k >> 1) * 2 + sub;   // 0..63
    const int b  = bq * 64 + bl;
    const float4 v = *(const float4*)(emb +
        ((size_t)(t * BATCH + b) * QCOLS + (size_t)c * DIM + col * 4));

    float mx = fmaxf(fmaxf(v.x, v.y), fmaxf(v.z, v.w));
#pragma unroll
    for (int off = 1; off < 32; off <<= 1) mx = fmaxf(mx, __shfl_xor(mx, off));
    float e0 = __expf(v.x - mx), e1 = __expf(v.y - mx);
    float e2 = __expf(v.z - mx), e3 = __expf(v.w - mx);
    float s = (e0 + e1) + (e2 + e3);
#pragma unroll
    for (int off = 1; off < 32; off <<= 1) s += __shfl_xor(s, off);
    const float inv = 1.0f / s;
    const float q0 = e0 * inv, q1 = e1 * inv, q2 = e2 * inv, q3 = e3 * inv;

    if (t == 0) { qa.x = q0; qa.y = q1; qa.z = q2; qa.w = q3; }
    else        { dot += qa.x * q0 + qa.y * q1 + qa.z * q2 + qa.w * q3; }

    int pk = __builtin_amdgcn_cvt_pk_fp8_f32(q0 * q0 * FP8SCALE,
                                             q1 * q1 * FP8SCALE, 0, false);
    pk = __builtin_amdgcn_cvt_pk_fp8_f32(q2 * q2 * FP8SCALE,
                                         q3 * q3 * FP8SCALE, pk, true);
    T32[(t * 64 + bl) * 33 + col] = (uint32_t)pk;
  }
  __syncthreads();

  // write-out: 1024 chunks of 16 B, PLAIN order: chunk b16 = b [b16*16,+16)
#pragma unroll
  for (int it = 0; it < 4; ++it) {
    int ch = it * 256 + tid;               // 0..1023
    int t = ch >> 9, d = (ch >> 2) & 127, b16 = ch & 3;
    const int dq = d >> 2, sh = (d & 3) * 8;
    uint32_t w0 = 0, w1 = 0, w2 = 0, w3 = 0;
#pragma unroll
    for (int r = 0; r < 4; ++r) {
      w0 |= ((T32[(t * 64 + b16 * 16 +  0 + r) * 33 + dq] >> sh) & 0xFFu) << (8 * r);
      w1 |= ((T32[(t * 64 + b16 * 16 +  4 + r) * 33 + dq] >> sh) & 0xFFu) << (8 * r);
      w2 |= ((T32[(t * 64 + b16 * 16 +  8 + r) * 33 + dq] >> sh) & 0xFFu) << (8 * r);
      w3 |= ((T32[(t * 64 + b16 * 16 + 12 + r) * 33 + dq] >> sh) & 0xFFu) << (8 * r);
    }
    size_t off = (size_t)t * TSTRB + (size_t)(c * DIM + d) * BATCH +
                 (size_t)bq * 64 + b16 * 16;
    uint4 o; o.x = w0; o.y = w1; o.z = w2; o.w = w3;
    *(uint4*)(q2t + off) = o;
  }

#pragma unroll
  for (int off = 1; off < 64; off <<= 1) dot += __shfl_xor(dot, off);
  if (lane == 0) red[w] = dot;
  __syncthreads();
  if (tid == 0) dotPart[blockIdx.y * 8 + blockIdx.x] = red[0] + red[1] + red[2] + red[3];
}

// ---------------------------------------------------------------------------
// Kernel 2: TWO-PAIR shared-A Gram. Block = (J; I1=J+1+2k, I2=I1+1):
// stages one A panel (J) + two B panels (I1,I2) per K-chunk (24 KB/step).
// Waves {0,1} compute pair (J,I1), waves {2,3} pair (J,I2); each wave owns
// a 64x128 tile -> acc[2][4], 8 MFMA per step with only 12 ds_read_b128
// (1.5 reads/MFMA vs 2.0 before — LDS-read pipe was 20us, the largest).
// Validated R2 schedule: 3 bufs (72 KB -> 2 blocks/CU), ONE s_barrier/step,
// counted vmcnt(6) (6 staging loads/thread/step), distance-2 prefetch
// (stage(m+2) overwrites buf[(m-1)%3] whose reads drained before
// barrier(m)), setprio around the MFMA cluster, FSQRT harvest.
// 1024 blocks = 4x256 CUs exact (no tail), = 128x8 exact XCD decode.
// Singleton blocks (I1==63): waves 2,3 stage but skip compute (take).
// ---------------------------------------------------------------------------
__global__ __launch_bounds__(256) void gram_sqrt_kernel(
    const uint8_t* __restrict__ q2t, float* __restrict__ Spart) {
  __shared__ uint8_t L[3 * 24576 + 32];  // buf k at k*24576: A@0 B1@8192 B2@16384

  // ---- decode: XCD partition (1024 = 128*8 exact) + (J, k) ----
  int sidx = ((int)blockIdx.x & 7) * 128 + ((int)blockIdx.x >> 3);
  int q = sidx, J = 0;
  while (q >= ((64 - J) >> 1)) { q -= (64 - J) >> 1; ++J; }
  const int I1 = J + 1 + 2 * q;
  const int I2 = I1 + 1;                     // may be 64 (singleton)
  const bool single = (I2 > 63);

  const uint8_t* baseA  = q2t + (size_t)J * (DIM * BATCH);   // 64 KB panels
  const uint8_t* baseB1 = q2t + (size_t)I1 * (DIM * BATCH);
  const uint8_t* baseB2 = q2t + (size_t)(single ? I1 : I2) * (DIM * BATCH);

  const int tid  = threadIdx.x;
  const int lane = tid & 63, w = tid >> 6;
  const int wm = w & 1, pr = w >> 1;         // wave row-half, pair index

  // staging: thread covers rows rs and rs+64 of each panel, phys p=tid&3,
  // source chunk c=(p-rot(rs))&3. rot(rs+64)==rot(rs) (64+16 ≡ 0 mod 4).
  const int rs   = tid >> 2;
  const int rotS = (rs + (rs >> 2)) & 3;
  const int cs   = ((tid & 3) - rotS) & 3;
  const size_t g0 = (size_t)rs * BATCH + cs * 16;
  const size_t g1 = (size_t)(rs + 64) * BATCH + cs * 16;
  uint8_t* Lb = L;
  const int ldsw = w * 1024;   // wave-uniform dest base within a 4 KB round

  // reader: lane h needs source chunks {2h,2h+1} at phys ((q+rot)&3)*16;
  // rot depends only on r31 (row bases are multiples of 32).
  const int h = lane >> 5, r31 = lane & 31;
  const int rot = (r31 + (r31 >> 2)) & 3;
  const int ro1 = ((2 * h + rot) & 3) * 16;
  const int ro2 = ((2 * h + 1 + rot) & 3) * 16;
  const int ArO = (wm * 64 + r31) * 64;            // + g*2048 (g=0,1)
  const int BrO = 8192 + pr * 8192 + r31 * 64;     // + c*2048 (c=0..3)

  const bool take = !(single && pr == 1);

  f32x16 acc[2][4];
#pragma unroll
  for (int i = 0; i < 2; ++i)
#pragma unroll
    for (int j = 0; j < 4; ++j) acc[i][j] = (f32x16)(0.f);

  float S0 = 0.f, S1 = 0.f;

#define CHOFF64(i) ((size_t)((i) >> 3) * TSTRB + (size_t)((i) & 7) * 64)
#define STAGE(bufb, ck) do {                                        \
    ld_lds16(baseA  + (ck) + g0, Lb + (bufb)         + ldsw);       \
    ld_lds16(baseA  + (ck) + g1, Lb + (bufb) +  4096 + ldsw);       \
    ld_lds16(baseB1 + (ck) + g0, Lb + (bufb) +  8192 + ldsw);       \
    ld_lds16(baseB1 + (ck) + g1, Lb + (bufb) + 12288 + ldsw);       \
    ld_lds16(baseB2 + (ck) + g0, Lb + (bufb) + 16384 + ldsw);       \
    ld_lds16(baseB2 + (ck) + g1, Lb + (bufb) + 20480 + ldsw);       \
  } while (0)
#define MFMA(a, b, c) __builtin_amdgcn_mfma_scale_f32_32x32x64_f8f6f4(        \
    (a), (b), (c), 0, 0, 0, 0x7F7F7F7F, 0, 0x7F7F7F7F)
#define CAT8(lo, hi) __builtin_shufflevector((lo), (hi), 0, 1, 2, 3, 4, 5, 6, 7)

  // prologue: chunks 0,1 into buf0,buf1 (12 loads/thread in flight)
  STAGE(0, CHOFF64(0));
  STAGE(24576, CHOFF64(1));

#pragma unroll
  for (int m = 0; m < 16; ++m) {
    // stage(m) landed (only stage(m+1)'s 6 loads may remain outstanding)
    if (m < 15) VM6_BAR(); else VM0_BAR();

    // prefetch chunk m+2 into buf (m+2)%3 == buf (m-1)%3 (reads drained)
    if (m < 14) STAGE(((m + 2) % 3) * 24576, CHOFF64(m + 2));

    if (take) {
      const int be = (m % 3) * 24576;
      i32x8 af[2], bf[4];
#pragma unroll
      for (int g = 0; g < 2; ++g) {
        i32x4 lo = *(const i32x4*)(Lb + be + ArO + g * 2048 + ro1);
        i32x4 hi = *(const i32x4*)(Lb + be + ArO + g * 2048 + ro2);
        af[g] = CAT8(lo, hi);
      }
#pragma unroll
      for (int c = 0; c < 4; ++c) {
        i32x4 lo = *(const i32x4*)(Lb + be + BrO + c * 2048 + ro1);
        i32x4 hi = *(const i32x4*)(Lb + be + BrO + c * 2048 + ro2);
        bf[c] = CAT8(lo, hi);
      }
      __builtin_amdgcn_s_setprio(1);
#pragma unroll
      for (int g = 0; g < 2; ++g)
#pragma unroll
        for (int c = 0; c < 4; ++c)
          acc[g][c] = MFMA(af[g], bf[c], acc[g][c]);
      __builtin_amdgcn_s_setprio(0);
    }

    if (m == 7) {                       // harvest tensor 0, reset acc
      if (take) {
        float p0 = 0.f, p1 = 0.f, p2 = 0.f, p3 = 0.f;
#pragma unroll
        for (int i = 0; i < 2; ++i)
#pragma unroll
          for (int j = 0; j < 4; ++j)
#pragma unroll
            for (int e = 0; e < 16; e += 4) {
              p0 += FSQRT(acc[i][j][e    ]);
              p1 += FSQRT(acc[i][j][e + 1]);
              p2 += FSQRT(acc[i][j][e + 2]);
              p3 += FSQRT(acc[i][j][e + 3]);
            }
        S0 = (p0 + p1) + (p2 + p3);
      }
#pragma unroll
      for (int i = 0; i < 2; ++i)
#pragma unroll
        for (int j = 0; j < 4; ++j) acc[i][j] = (f32x16)(0.f);
    }
  }

  // harvest tensor 1
  if (take) {
    float p0 = 0.f, p1 = 0.f, p2 = 0.f, p3 = 0.f;
#pragma unroll
    for (int i = 0; i < 2; ++i)
#pragma unroll
      for (int j = 0; j < 4; ++j)
#pragma unroll
        for (int e = 0; e < 16; e += 4) {
          p0 += FSQRT(acc[i][j][e    ]);
          p1 += FSQRT(acc[i][j][e + 1]);
          p2 += FSQRT(acc[i][j][e + 2]);
          p3 += FSQRT(acc[i][j][e + 3]);
        }
    S1 = (p0 + p1) + (p2 + p3);
  }

  // G was scaled by 256*256 -> sqrt scaled by 256
  float local = (S0 + S1) * (1.0f / 256.0f);
#pragma unroll
  for (int off = 1; off < 64; off <<= 1) local += __shfl_xor(local, off);
  float* fred = (float*)(L + 3 * 24576);
  if (lane == 0) fred[w] = local;
  __syncthreads();
  if (tid == 0) Spart[blockIdx.x] = fred[0] + fred[1] + fred[2] + fred[3];
}

// ---------------------------------------------------------------------------
// Kernel 3: reduce partials and combine.
// P[0..511] = dot partials, P[512..512+1023] = S partials (per block).
// loss = -dot/(B*N_C) - S/((N_C^2-N_C)*sqrt(B))
// ---------------------------------------------------------------------------
__global__ __launch_bounds__(256) void finalize_kernel(
    const float* __restrict__ P, float* __restrict__ out) {
  __shared__ float rd[8];
  const int tid = threadIdx.x;
  float d = 0.f, s = 0.f;
  for (int i = tid; i < 512; i += 256) d += P[i];
  for (int i = tid; i < NBLK2; i += 256) s += P[512 + i];
#pragma unroll
  for (int off = 1; off < 64; off <<= 1) { d += __shfl_xor(d, off); s += __shfl_xor(s, off); }
  const int w = tid >> 6;
  if ((tid & 63) == 0) { rd[w] = d; rd[4 + w] = s; }
  __syncthreads();
  if (tid == 0) {
    float dt = rd[0] + rd[1] + rd[2] + rd[3];
    float st = rd[4] + rd[5] + rd[6] + rd[7];
    out[0] = -dt / 32768.0f - st / (4032.0f * 22.62741699796952f);
  }
}

extern "C" void kernel_launch(void* const* d_in, const int* in_sizes, int n_in,
                              void* d_out, int out_size, void* d_ws, size_t ws_size,
                              hipStream_t stream) {
  const float* emb = (const float*)d_in[0];
  float* out = (float*)d_out;
  float* P = (float*)d_ws;                                 // 512 + 1024 partials
  uint8_t* q2t = (uint8_t*)d_ws + 16384;                   // 2 x 8192 x 512 fp8

  softmax_q2_kernel<<<dim3(8, 64), 256, 0, stream>>>(emb, q2t, P);
  gram_sqrt_kernel<<<dim3(NBLK2), 256, 0, stream>>>(q2t, P + 512);
  finalize_kernel<<<1, 256, 0, stream>>>(P, out);
}